// Round 4
// baseline (310.449 us; speedup 1.0000x reference)
//
#include <hip/hip_runtime.h>
#include <hip/hip_bf16.h>

// GDGCN: out[b,c,m,t] = sum_n softmax_row(relu(t1 nv2^T))[n,m] * x[b,c,n,t]
// t1 = nv1 @ (sum_d tv[d] k[d,:,:]);  N=8192, D=32, cols = B*C*T = 192.
// Round-4 strategy: FULLY FUSED main kernel. E tiles are computed by MFMA in
// C-layout D[n][m] (lane holds 4 consecutive n of one m-row), transformed to
// the accumulate-MFMA's B-operand layout via a WAVE-PRIVATE LDS round-trip
// (1 x ds_write_b64 x2 + 1 x ds_read_b128, 2-way banks = free). No barriers,
// no 128 MB Et materialization, no atomics in hot loops.

#define NN 8192
#define DD 32
#define TT 12
#define NSPLIT 8
#define CHUNK (NN / NSPLIT)

typedef __attribute__((ext_vector_type(8))) short bf16x8;
typedef __attribute__((ext_vector_type(4))) short bf16x4;
typedef __attribute__((ext_vector_type(4))) float f32x4;

static __device__ __forceinline__ unsigned short f2bf(float f) {
  unsigned int u = __float_as_uint(f);
  u = (u + 0x7FFFu + ((u >> 16) & 1u)) >> 16;  // RNE bf16
  return (unsigned short)u;
}

// ---- fused: core = tv.k ; t1 = nv1@core (bf16) ; nv2 -> bf16 ----
__global__ __launch_bounds__(256) void k_prep(const float* __restrict__ nv1,
                                              const float* __restrict__ nv2,
                                              const float* __restrict__ timevec,
                                              const float* __restrict__ kk,
                                              const int* __restrict__ tind,
                                              unsigned short* __restrict__ t1b,
                                              unsigned short* __restrict__ nv2b) {
  __shared__ float cs[1024];
  const int tid = threadIdx.x;
  const float* tv = timevec + (size_t)tind[0] * DD;
  for (int idx = tid; idx < 1024; idx += 256) {
    float acc = 0.f;
#pragma unroll
    for (int d = 0; d < DD; ++d) acc += tv[d] * kk[d * 1024 + idx];
    cs[idx] = acc;
  }
  __syncthreads();
  const int nbase = blockIdx.x * 128;
  const int f = tid & 31, sub = tid >> 5;
#pragma unroll 4
  for (int it = 0; it < 16; ++it) {
    const int n = nbase + it * 8 + sub;
    const float* nr = nv1 + (size_t)n * DD;
    float acc = 0.f;
#pragma unroll
    for (int e = 0; e < DD; ++e) acc += nr[e] * cs[e * DD + f];
    t1b[(size_t)n * DD + f] = f2bf(acc);
  }
#pragma unroll 4
  for (int it = 0; it < 16; ++it) {
    const int idx = nbase * DD + it * 256 + tid;
    nv2b[idx] = f2bf(nv2[idx]);
  }
}

// ---- sums[n] += sum_m exp(relu(t1[n].nv2[m]))  (m-split x4, ILP-4 MFMA) ----
__global__ __launch_bounds__(256) void k_stats(const unsigned short* __restrict__ t1b,
                                               const unsigned short* __restrict__ nv2b,
                                               float* __restrict__ sums) {
  const int tid = threadIdx.x;
  const int w = tid >> 6, lane = tid & 63, q = lane >> 4, i16 = lane & 15;
  const int nbase = blockIdx.x * 64 + w * 16;
  bf16x8 a = *(const bf16x8*)(t1b + (size_t)(nbase + i16) * DD + q * 8);
  const f32x4 z4 = {0.f, 0.f, 0.f, 0.f};
  float s[4] = {0.f, 0.f, 0.f, 0.f};
  const int m0 = blockIdx.y * 2048;
  for (int mt = m0; mt < m0 + 2048; mt += 64) {
#pragma unroll
    for (int u = 0; u < 4; ++u) {
      bf16x8 b = *(const bf16x8*)(nv2b + (size_t)(mt + u * 16 + i16) * DD + q * 8);
      f32x4 d = __builtin_amdgcn_mfma_f32_16x16x32_bf16(a, b, z4, 0, 0, 0);
#pragma unroll
      for (int r = 0; r < 4; ++r) s[r] += __expf(fmaxf(d[r], 0.f));
    }
  }
#pragma unroll
  for (int r = 0; r < 4; ++r)
    for (int off = 1; off < 16; off <<= 1) s[r] += __shfl_xor(s[r], off, 64);
  if (i16 == 0) {
#pragma unroll
    for (int r = 0; r < 4; ++r) atomicAdd(&sums[nbase + q * 4 + r], s[r]);
  }
}

// ---- yT[col][n] = bf16(x[bc][n][t] / sums[n]) via LDS transpose ----
__global__ __launch_bounds__(256) void k_y(const float* __restrict__ x,
                                           const float* __restrict__ sums,
                                           unsigned short* __restrict__ yT) {
  __shared__ float xs[3072];
  const int tid = threadIdx.x;
  const int n0 = blockIdx.x * 256;
  const int bc = blockIdx.y;
  const float* xp = x + (size_t)bc * NN * TT + (size_t)n0 * TT;
#pragma unroll
  for (int j = 0; j < 12; ++j) xs[j * 256 + tid] = xp[j * 256 + tid];
  __syncthreads();
  const float rinv = 1.0f / sums[n0 + tid];
#pragma unroll
  for (int t = 0; t < 12; ++t)
    yT[(size_t)(bc * TT + t) * NN + n0 + tid] = f2bf(xs[tid * 12 + t] * rinv);
}

// ---- fused main: part[nc][col][m] = sum_{n in chunk} E[n][m] * y[col][n] ----
// grid (128 m-blocks of 64, NSPLIT chunks); 4 waves; wave = 16 m x all 192 cols.
// Per 32-n iter: 2 logit MFMAs (D[n][m]) -> exp -> wave-private LDS transform
// -> B-frag -> 12 accumulate MFMAs. No barriers, no block-level LDS sharing.
__global__ __launch_bounds__(256, 3) void k_fused(const unsigned short* __restrict__ t1b,
                                                  const unsigned short* __restrict__ nv2b,
                                                  const unsigned short* __restrict__ yT,
                                                  float* __restrict__ part) {
  const int tid = threadIdx.x;
  const int w = tid >> 6, lane = tid & 63, q = lane >> 4, i16 = lane & 15;
  const int mw = blockIdx.x * 64 + w * 16;  // wave's 16-m subtile
  const int nt0 = blockIdx.y * CHUNK;

  __shared__ unsigned short Ew[4][16][40];  // wave-private [m-local][n-local+pad8]

  // loop-invariant logit B-frag: B[d][m-local=i16] = nv2[mw+i16][d=q*8+j]
  const bf16x8 b_nv2 = *(const bf16x8*)(nv2b + (size_t)(mw + i16) * DD + q * 8);

  f32x4 acc[12];
#pragma unroll
  for (int c = 0; c < 12; ++c) acc[c] = (f32x4){0.f, 0.f, 0.f, 0.f};
  const f32x4 z4 = {0.f, 0.f, 0.f, 0.f};

  // t1 A-frag prefetch: A[n-local=i16][d=q*8+j] = t1[nt+i16][d]
  bf16x8 a0 = *(const bf16x8*)(t1b + (size_t)(nt0 + i16) * DD + q * 8);
  bf16x8 a1 = *(const bf16x8*)(t1b + (size_t)(nt0 + 16 + i16) * DD + q * 8);

  for (int nt = nt0; nt < nt0 + CHUNK; nt += 32) {
    // y A-frags for this iter (b128, straight from L2-resident yT)
    bf16x8 yfr[12];
#pragma unroll
    for (int c = 0; c < 12; ++c)
      yfr[c] = *(const bf16x8*)(yT + (size_t)(c * 16 + i16) * NN + nt + q * 8);

    // logits: D[n-local][m-local], lane holds n = nt + (16*h) + q*4+r, m = mw+i16
    f32x4 d1 = __builtin_amdgcn_mfma_f32_16x16x32_bf16(a0, b_nv2, z4, 0, 0, 0);
    f32x4 d2 = __builtin_amdgcn_mfma_f32_16x16x32_bf16(a1, b_nv2, z4, 0, 0, 0);

    // prefetch next iter's t1 (clamped in-bounds on last iter)
    const int ntn = (nt + 32 < nt0 + CHUNK) ? nt + 32 : nt0;
    a0 = *(const bf16x8*)(t1b + (size_t)(ntn + i16) * DD + q * 8);
    a1 = *(const bf16x8*)(t1b + (size_t)(ntn + 16 + i16) * DD + q * 8);

    // E = exp(relu(.)) -> wave-private LDS in [m][n] order
    bf16x4 e1, e2;
#pragma unroll
    for (int r = 0; r < 4; ++r) {
      e1[r] = (short)f2bf(__expf(fmaxf(d1[r], 0.f)));
      e2[r] = (short)f2bf(__expf(fmaxf(d2[r], 0.f)));
    }
    *(bf16x4*)&Ew[w][i16][q * 4] = e1;        // ds_write_b64 (2-way banks: free)
    *(bf16x4*)&Ew[w][i16][16 + q * 4] = e2;
    // B-frag: B[k=n-local=q*8+j][m-local=i16]  (ds_read_b128, same-wave order)
    const bf16x8 efr = *(const bf16x8*)&Ew[w][i16][q * 8];

#pragma unroll
    for (int c = 0; c < 12; ++c)
      acc[c] = __builtin_amdgcn_mfma_f32_16x16x32_bf16(yfr[c], efr, acc[c], 0, 0, 0);
  }

  // epilogue: lane holds col = c*16 + q*4 + r, m = mw + i16 (coalesced over i16)
  float* pp = part + (size_t)blockIdx.y * 192 * NN;
#pragma unroll
  for (int c = 0; c < 12; ++c) {
    const int colbase = c * 16 + q * 4;
#pragma unroll
    for (int r = 0; r < 4; ++r)
      pp[(size_t)(colbase + r) * NN + mw + i16] = acc[c][r];
  }
}

// ---- reduce NSPLIT partials + transpose to out[bc][m][t] ----
__global__ __launch_bounds__(256) void k_reduce(const float* __restrict__ part,
                                                float* __restrict__ out) {
  __shared__ float os[3072];
  const int tid = threadIdx.x;
  const int m0 = blockIdx.x * 256;
  const int bc = blockIdx.y;
#pragma unroll
  for (int t = 0; t < 12; ++t) {
    const int col = bc * TT + t;
    float s = 0.f;
#pragma unroll
    for (int nc = 0; nc < NSPLIT; ++nc)
      s += part[((size_t)nc * 192 + col) * NN + m0 + tid];
    os[tid * 12 + t] = s;
  }
  __syncthreads();
  float* op = out + (size_t)bc * NN * TT + (size_t)m0 * TT;
#pragma unroll
  for (int j = 0; j < 12; ++j) op[j * 256 + tid] = os[j * 256 + tid];
}

extern "C" void kernel_launch(void* const* d_in, const int* in_sizes, int n_in,
                              void* d_out, int out_size, void* d_ws, size_t ws_size,
                              hipStream_t stream) {
  const float* x = (const float*)d_in[0];
  const float* nv1 = (const float*)d_in[1];
  const float* nv2 = (const float*)d_in[2];
  const float* tv = (const float*)d_in[3];
  const float* kk = (const float*)d_in[4];
  const int* tind = (const int*)d_in[5];
  float* out = (float*)d_out;

  char* ws = (char*)d_ws;
  unsigned short* t1b  = (unsigned short*)(ws);            //  524288 B
  unsigned short* nv2b = (unsigned short*)(ws + 524288);   //  524288 B
  float* sums          = (float*)(ws + 1048576);           //   32768 B
  unsigned short* yT   = (unsigned short*)(ws + 1081344);  // 3145728 B -> 4227072
  float* part          = (float*)(ws + 4227072);           // 50331648 B -> 54558720 (~55 MB)

  hipMemsetAsync(sums, 0, NN * sizeof(float), stream);
  k_prep<<<64, 256, 0, stream>>>(nv1, nv2, tv, kk, tind, t1b, nv2b);
  k_stats<<<dim3(128, 4), 256, 0, stream>>>(t1b, nv2b, sums);
  k_y<<<dim3(32, 16), 256, 0, stream>>>(x, sums, yT);
  k_fused<<<dim3(128, NSPLIT), 256, 0, stream>>>(t1b, nv2b, yT, part);
  k_reduce<<<dim3(32, 16), 256, 0, stream>>>(part, out);
}

// Round 5
// 191.404 us; speedup vs baseline: 1.6220x; 1.6220x over previous
//
#include <hip/hip_runtime.h>
#include <hip/hip_bf16.h>

// GDGCN: out[b,c,m,t] = sum_n softmax_row(relu(t1 nv2^T))[n,m] * x[b,c,n,t]
// t1 = nv1 @ (sum_d tv[d] k[d,:,:]);  N=8192, D=32, cols = B*C*T = 192.
// Round-5: k_mega = big-stage fused GEMM. Per block: 128 m x 1024 n chunk.
// E-tile (128m x 64n bf16) generated by MFMA+exp into double-buffered LDS,
// ONE barrier per stage; accumulate phase reads E b128 from LDS and y b128
// from L2. E never touches HBM (R3's 256 MB tax eliminated); stage is large
// enough that exp-VALU, MFMA and loads each have 100s of cycles of
// independent work (R1/R2/R4's thin-iteration serialization eliminated).

#define NN 8192
#define DD 32
#define TT 12
#define NSPLIT 8
#define CHUNK 1024  // n per block
#define ESTR 72     // LDS row stride (ushorts): 144 B = 36 banks; minimal aliasing

typedef __attribute__((ext_vector_type(8))) short bf16x8;
typedef __attribute__((ext_vector_type(4))) short bf16x4;
typedef __attribute__((ext_vector_type(4))) float f32x4;

static __device__ __forceinline__ unsigned short f2bf(float f) {
  unsigned int u = __float_as_uint(f);
  u = (u + 0x7FFFu + ((u >> 16) & 1u)) >> 16;  // RNE bf16
  return (unsigned short)u;
}

// ---- fused: core = tv.k ; t1 = nv1@core (bf16) ; nv2 -> bf16 ----
__global__ __launch_bounds__(256) void k_prep(const float* __restrict__ nv1,
                                              const float* __restrict__ nv2,
                                              const float* __restrict__ timevec,
                                              const float* __restrict__ kk,
                                              const int* __restrict__ tind,
                                              unsigned short* __restrict__ t1b,
                                              unsigned short* __restrict__ nv2b) {
  __shared__ float cs[1024];
  const int tid = threadIdx.x;
  const float* tv = timevec + (size_t)tind[0] * DD;
  for (int idx = tid; idx < 1024; idx += 256) {
    float acc = 0.f;
#pragma unroll
    for (int d = 0; d < DD; ++d) acc += tv[d] * kk[d * 1024 + idx];
    cs[idx] = acc;
  }
  __syncthreads();
  const int nbase = blockIdx.x * 128;
  const int f = tid & 31, sub = tid >> 5;
#pragma unroll 4
  for (int it = 0; it < 16; ++it) {
    const int n = nbase + it * 8 + sub;
    const float* nr = nv1 + (size_t)n * DD;
    float acc = 0.f;
#pragma unroll
    for (int e = 0; e < DD; ++e) acc += nr[e] * cs[e * DD + f];
    t1b[(size_t)n * DD + f] = f2bf(acc);
  }
#pragma unroll 4
  for (int it = 0; it < 16; ++it) {
    const int idx = nbase * DD + it * 256 + tid;
    nv2b[idx] = f2bf(nv2[idx]);
  }
}

// ---- sums[n] += sum_m exp(relu(t1[n].nv2[m]))  (m-split x4, ILP-4 MFMA) ----
__global__ __launch_bounds__(256) void k_stats(const unsigned short* __restrict__ t1b,
                                               const unsigned short* __restrict__ nv2b,
                                               float* __restrict__ sums) {
  const int tid = threadIdx.x;
  const int w = tid >> 6, lane = tid & 63, q = lane >> 4, i16 = lane & 15;
  const int nbase = blockIdx.x * 64 + w * 16;
  bf16x8 a = *(const bf16x8*)(t1b + (size_t)(nbase + i16) * DD + q * 8);
  const f32x4 z4 = {0.f, 0.f, 0.f, 0.f};
  float s[4] = {0.f, 0.f, 0.f, 0.f};
  const int m0 = blockIdx.y * 2048;
  for (int mt = m0; mt < m0 + 2048; mt += 64) {
#pragma unroll
    for (int u = 0; u < 4; ++u) {
      bf16x8 b = *(const bf16x8*)(nv2b + (size_t)(mt + u * 16 + i16) * DD + q * 8);
      f32x4 d = __builtin_amdgcn_mfma_f32_16x16x32_bf16(a, b, z4, 0, 0, 0);
#pragma unroll
      for (int r = 0; r < 4; ++r) s[r] += __expf(fmaxf(d[r], 0.f));
    }
  }
#pragma unroll
  for (int r = 0; r < 4; ++r)
    for (int off = 1; off < 16; off <<= 1) s[r] += __shfl_xor(s[r], off, 64);
  if (i16 == 0) {
#pragma unroll
    for (int r = 0; r < 4; ++r) atomicAdd(&sums[nbase + q * 4 + r], s[r]);
  }
}

// ---- yT[col][n] = bf16(x[bc][n][t] / sums[n]) via LDS transpose ----
__global__ __launch_bounds__(256) void k_y(const float* __restrict__ x,
                                           const float* __restrict__ sums,
                                           unsigned short* __restrict__ yT) {
  __shared__ float xs[3072];
  const int tid = threadIdx.x;
  const int n0 = blockIdx.x * 256;
  const int bc = blockIdx.y;
  const float* xp = x + (size_t)bc * NN * TT + (size_t)n0 * TT;
#pragma unroll
  for (int j = 0; j < 12; ++j) xs[j * 256 + tid] = xp[j * 256 + tid];
  __syncthreads();
  const float rinv = 1.0f / sums[n0 + tid];
#pragma unroll
  for (int t = 0; t < 12; ++t)
    yT[(size_t)(bc * TT + t) * NN + n0 + tid] = f2bf(xs[tid * 12 + t] * rinv);
}

// ---- k_mega: part[nc][col][m] = sum_{n in chunk} E[n][m] * y[col][n] ----
// grid (64 m-blocks of 128, 8 chunks of 1024 n); 4 waves.
// Stage = 64 n. Generation: wave w computes E rows [w*32, w*32+32) x 64 n
// via 8 logit MFMAs (D[n][m]) + exp + b64 LDS writes. Accumulate: wave
// (wc=w&1, wm=w>>1) does 6 coltiles x 4 msubs (m in [wm*64, wm*64+64)),
// 48 MFMAs/stage; y-frags from L2, e-frags b128 from LDS. One barrier/stage.
__global__ __launch_bounds__(256, 2) void k_mega(const unsigned short* __restrict__ t1b,
                                                 const unsigned short* __restrict__ nv2b,
                                                 const unsigned short* __restrict__ yT,
                                                 float* __restrict__ part) {
  const int tid = threadIdx.x;
  const int w = tid >> 6, lane = tid & 63, q = lane >> 4, i16 = lane & 15;
  const int wc = w & 1, wm = w >> 1;
  const int mb = blockIdx.x * 128;
  const int nt0 = blockIdx.y * CHUNK;

  __shared__ unsigned short Ew[2][128][ESTR];  // 36864 B

  // generation B-frags (loop-invariant): B[d][m=i16] = nv2[mb + w*32 + g*16 + i16][d]
  bf16x8 bg[2];
#pragma unroll
  for (int g = 0; g < 2; ++g)
    bg[g] = *(const bf16x8*)(nv2b + (size_t)(mb + w * 32 + g * 16 + i16) * DD + q * 8);

  const f32x4 z4 = {0.f, 0.f, 0.f, 0.f};
  f32x4 acc[6][4];
#pragma unroll
  for (int c = 0; c < 6; ++c)
#pragma unroll
    for (int ms = 0; ms < 4; ++ms) acc[c][ms] = (f32x4){0.f, 0.f, 0.f, 0.f};

  // ---- prologue: generate stage 0 into buf 0 ----
  {
    bf16x8 atL[4];
#pragma unroll
    for (int s = 0; s < 4; ++s)
      atL[s] = *(const bf16x8*)(t1b + (size_t)(nt0 + s * 16 + i16) * DD + q * 8);
#pragma unroll
    for (int g = 0; g < 2; ++g)
#pragma unroll
      for (int s = 0; s < 4; ++s) {
        f32x4 d = __builtin_amdgcn_mfma_f32_16x16x32_bf16(atL[s], bg[g], z4, 0, 0, 0);
        bf16x4 e;
#pragma unroll
        for (int r = 0; r < 4; ++r) e[r] = (short)f2bf(__expf(fmaxf(d[r], 0.f)));
        // lane holds n-local = s*16 + q*4 + r, m-local = w*32 + g*16 + i16
        *(bf16x4*)&Ew[0][w * 32 + g * 16 + i16][s * 16 + q * 4] = e;
      }
  }
  __syncthreads();

  int p = 0;
  for (int st = 0; st < 16; ++st, p ^= 1) {
    const int nt = nt0 + st * 64;
    const bool more = (st < 15);

    // next stage's t1 A-frags (issued first for latency)
    bf16x8 atn[4];
    if (more) {
#pragma unroll
      for (int s = 0; s < 4; ++s)
        atn[s] = *(const bf16x8*)(t1b + (size_t)(nt + 64 + s * 16 + i16) * DD + q * 8);
    }

    // ---- half 0 y-frags + e-frags ----
    bf16x8 yfr0[6];
#pragma unroll
    for (int c = 0; c < 6; ++c)
      yfr0[c] = *(const bf16x8*)(yT + (size_t)((wc * 6 + c) * 16 + i16) * NN + nt + q * 8);
    bf16x8 efr0[4];
#pragma unroll
    for (int ms = 0; ms < 4; ++ms)
      efr0[ms] = *(const bf16x8*)&Ew[p][wm * 64 + ms * 16 + i16][q * 8];

    // generation logit MFMAs for stage st+1 (results consumed later by exp)
    f32x4 d[2][4];
    if (more) {
#pragma unroll
      for (int g = 0; g < 2; ++g)
#pragma unroll
        for (int s = 0; s < 4; ++s)
          d[g][s] = __builtin_amdgcn_mfma_f32_16x16x32_bf16(atn[s], bg[g], z4, 0, 0, 0);
    }

    // half 1 loads issued while half-0 MFMAs run
    bf16x8 yfr1[6];
#pragma unroll
    for (int c = 0; c < 6; ++c)
      yfr1[c] = *(const bf16x8*)(yT + (size_t)((wc * 6 + c) * 16 + i16) * NN + nt + 32 + q * 8);
    bf16x8 efr1[4];
#pragma unroll
    for (int ms = 0; ms < 4; ++ms)
      efr1[ms] = *(const bf16x8*)&Ew[p][wm * 64 + ms * 16 + i16][32 + q * 8];

#pragma unroll
    for (int c = 0; c < 6; ++c)
#pragma unroll
      for (int ms = 0; ms < 4; ++ms)
        acc[c][ms] = __builtin_amdgcn_mfma_f32_16x16x32_bf16(yfr0[c], efr0[ms], acc[c][ms], 0, 0, 0);

    // exp/pack/store for stage st+1 into buf p^1 (VALU overlaps MFMA pipes)
    if (more) {
#pragma unroll
      for (int g = 0; g < 2; ++g)
#pragma unroll
        for (int s = 0; s < 4; ++s) {
          bf16x4 e;
#pragma unroll
          for (int r = 0; r < 4; ++r) e[r] = (short)f2bf(__expf(fmaxf(d[g][s][r], 0.f)));
          *(bf16x4*)&Ew[p ^ 1][w * 32 + g * 16 + i16][s * 16 + q * 4] = e;
        }
    }

#pragma unroll
    for (int c = 0; c < 6; ++c)
#pragma unroll
      for (int ms = 0; ms < 4; ++ms)
        acc[c][ms] = __builtin_amdgcn_mfma_f32_16x16x32_bf16(yfr1[c], efr1[ms], acc[c][ms], 0, 0, 0);

    __syncthreads();  // buf p reads done; buf p^1 writes visible
  }

  // epilogue: lane holds col = (wc*6+c)*16 + q*4 + r, m = mb + wm*64 + ms*16 + i16
  float* pp = part + (size_t)blockIdx.y * 192 * NN;
#pragma unroll
  for (int c = 0; c < 6; ++c)
#pragma unroll
    for (int ms = 0; ms < 4; ++ms) {
      const int colbase = (wc * 6 + c) * 16 + q * 4;
      const int m = mb + wm * 64 + ms * 16 + i16;
#pragma unroll
      for (int r = 0; r < 4; ++r)
        pp[(size_t)(colbase + r) * NN + m] = acc[c][ms][r];
    }
}

// ---- reduce NSPLIT partials + transpose to out[bc][m][t] ----
__global__ __launch_bounds__(256) void k_reduce(const float* __restrict__ part,
                                                float* __restrict__ out) {
  __shared__ float os[3072];
  const int tid = threadIdx.x;
  const int m0 = blockIdx.x * 256;
  const int bc = blockIdx.y;
#pragma unroll
  for (int t = 0; t < 12; ++t) {
    const int col = bc * TT + t;
    float s = 0.f;
#pragma unroll
    for (int nc = 0; nc < NSPLIT; ++nc)
      s += part[((size_t)nc * 192 + col) * NN + m0 + tid];
    os[tid * 12 + t] = s;
  }
  __syncthreads();
  float* op = out + (size_t)bc * NN * TT + (size_t)m0 * TT;
#pragma unroll
  for (int j = 0; j < 12; ++j) op[j * 256 + tid] = os[j * 256 + tid];
}

extern "C" void kernel_launch(void* const* d_in, const int* in_sizes, int n_in,
                              void* d_out, int out_size, void* d_ws, size_t ws_size,
                              hipStream_t stream) {
  const float* x = (const float*)d_in[0];
  const float* nv1 = (const float*)d_in[1];
  const float* nv2 = (const float*)d_in[2];
  const float* tv = (const float*)d_in[3];
  const float* kk = (const float*)d_in[4];
  const int* tind = (const int*)d_in[5];
  float* out = (float*)d_out;

  char* ws = (char*)d_ws;
  unsigned short* t1b  = (unsigned short*)(ws);            //  524288 B
  unsigned short* nv2b = (unsigned short*)(ws + 524288);   //  524288 B
  float* sums          = (float*)(ws + 1048576);           //   32768 B
  unsigned short* yT   = (unsigned short*)(ws + 1081344);  // 3145728 B -> 4227072
  float* part          = (float*)(ws + 4227072);           // 50331648 B -> 54558720 (~55 MB)

  hipMemsetAsync(sums, 0, NN * sizeof(float), stream);
  k_prep<<<64, 256, 0, stream>>>(nv1, nv2, tv, kk, tind, t1b, nv2b);
  k_stats<<<dim3(128, 4), 256, 0, stream>>>(t1b, nv2b, sums);
  k_y<<<dim3(32, 16), 256, 0, stream>>>(x, sums, yT);
  k_mega<<<dim3(64, NSPLIT), 256, 0, stream>>>(t1b, nv2b, yT, part);
  k_reduce<<<dim3(32, 16), 256, 0, stream>>>(part, out);
}

// Round 6
// 180.750 us; speedup vs baseline: 1.7176x; 1.0589x over previous
//
#include <hip/hip_runtime.h>
#include <hip/hip_bf16.h>

// GDGCN: out[b,c,m,t] = sum_n softmax_row(relu(t1 nv2^T))[n,m] * x[b,c,n,t]
// t1 = nv1 @ (sum_d tv[d] k[d,:,:]);  N=8192, D=32, cols = B*C*T = 192.
// R6: k_mega 512-thread blocks (16 waves/CU), t1 pre-scaled by log2(e) so
// E = exp2(max(logit,0)) is a single v_exp_f32. Stage = 128 m x 64 n in
// double-buffered LDS, 1 barrier/stage. y-duplication capped at 2x/block.

#define NN 8192
#define DD 32
#define TT 12
#define NSPLIT 8
#define CHUNK 1024
#define ESTR 72  // LDS row stride (ushort); b64-write 4/bank, b128-read 8/bank = data minimum

typedef __attribute__((ext_vector_type(8))) short bf16x8;
typedef __attribute__((ext_vector_type(4))) short bf16x4;
typedef __attribute__((ext_vector_type(4))) float f32x4;

static __device__ __forceinline__ unsigned short f2bf(float f) {
  unsigned int u = __float_as_uint(f);
  u = (u + 0x7FFFu + ((u >> 16) & 1u)) >> 16;  // RNE bf16
  return (unsigned short)u;
}

static __device__ __forceinline__ float fexp2(float x) {
#if __has_builtin(__builtin_amdgcn_exp2f)
  return __builtin_amdgcn_exp2f(x);
#else
  return __builtin_exp2f(x);
#endif
}

// ---- fused: core = tv.k ; t1 = (nv1@core)*log2e (bf16) ; nv2 -> bf16 ----
__global__ __launch_bounds__(256) void k_prep(const float* __restrict__ nv1,
                                              const float* __restrict__ nv2,
                                              const float* __restrict__ timevec,
                                              const float* __restrict__ kk,
                                              const int* __restrict__ tind,
                                              unsigned short* __restrict__ t1b,
                                              unsigned short* __restrict__ nv2b) {
  __shared__ float cs[1024];
  const int tid = threadIdx.x;
  const float* tv = timevec + (size_t)tind[0] * DD;
  for (int idx = tid; idx < 1024; idx += 256) {
    float acc = 0.f;
#pragma unroll
    for (int d = 0; d < DD; ++d) acc += tv[d] * kk[d * 1024 + idx];
    cs[idx] = acc;
  }
  __syncthreads();
  const int nbase = blockIdx.x * 128;
  const int f = tid & 31, sub = tid >> 5;
#pragma unroll 4
  for (int it = 0; it < 16; ++it) {
    const int n = nbase + it * 8 + sub;
    const float* nr = nv1 + (size_t)n * DD;
    float acc = 0.f;
#pragma unroll
    for (int e = 0; e < DD; ++e) acc += nr[e] * cs[e * DD + f];
    t1b[(size_t)n * DD + f] = f2bf(acc * 1.4426950408889634f);  // fold log2(e)
  }
#pragma unroll 4
  for (int it = 0; it < 16; ++it) {
    const int idx = nbase * DD + it * 256 + tid;
    nv2b[idx] = f2bf(nv2[idx]);
  }
}

// ---- sums[n] += sum_m exp2(relu(t1[n].nv2[m]))  grid (128 n, 8 m-chunks) ----
__global__ __launch_bounds__(256) void k_stats(const unsigned short* __restrict__ t1b,
                                               const unsigned short* __restrict__ nv2b,
                                               float* __restrict__ sums) {
  const int tid = threadIdx.x;
  const int w = tid >> 6, lane = tid & 63, q = lane >> 4, i16 = lane & 15;
  const int nbase = blockIdx.x * 64 + w * 16;
  bf16x8 a = *(const bf16x8*)(t1b + (size_t)(nbase + i16) * DD + q * 8);
  const f32x4 z4 = {0.f, 0.f, 0.f, 0.f};
  float s[4] = {0.f, 0.f, 0.f, 0.f};
  const int m0 = blockIdx.y * 1024;
  for (int mt = m0; mt < m0 + 1024; mt += 64) {
#pragma unroll
    for (int u = 0; u < 4; ++u) {
      bf16x8 b = *(const bf16x8*)(nv2b + (size_t)(mt + u * 16 + i16) * DD + q * 8);
      f32x4 d = __builtin_amdgcn_mfma_f32_16x16x32_bf16(a, b, z4, 0, 0, 0);
#pragma unroll
      for (int r = 0; r < 4; ++r) s[r] += fexp2(fmaxf(d[r], 0.f));
    }
  }
#pragma unroll
  for (int r = 0; r < 4; ++r)
    for (int off = 1; off < 16; off <<= 1) s[r] += __shfl_xor(s[r], off, 64);
  if (i16 == 0) {
#pragma unroll
    for (int r = 0; r < 4; ++r) atomicAdd(&sums[nbase + q * 4 + r], s[r]);
  }
}

// ---- yT[col][n] = bf16(x[bc][n][t] / sums[n]) via LDS transpose ----
__global__ __launch_bounds__(256) void k_y(const float* __restrict__ x,
                                           const float* __restrict__ sums,
                                           unsigned short* __restrict__ yT) {
  __shared__ float xs[3072];
  const int tid = threadIdx.x;
  const int n0 = blockIdx.x * 256;
  const int bc = blockIdx.y;
  const float* xp = x + (size_t)bc * NN * TT + (size_t)n0 * TT;
#pragma unroll
  for (int j = 0; j < 12; ++j) xs[j * 256 + tid] = xp[j * 256 + tid];
  __syncthreads();
  const float rinv = 1.0f / sums[n0 + tid];
#pragma unroll
  for (int t = 0; t < 12; ++t)
    yT[(size_t)(bc * TT + t) * NN + n0 + tid] = f2bf(xs[tid * 12 + t] * rinv);
}

// ---- k_mega: part[nc][col][m] = sum_{n in chunk} E[n][m] * y[col][n] ----
// grid (64 m-blocks of 128, 8 chunks of 1024 n); 512 threads = 8 waves.
// Gen: wave w -> E rows [w*16,w*16+16) x 64 n (4 MFMAs + 16 exp2/lane).
// Acc: wave (wc=w>>1, wm=w&1): coltiles [wc*3,wc*3+3) x m-subs wm*64+ms*16,
// 24 MFMAs/stage. One barrier/stage, double-buffered E in LDS.
__global__ __launch_bounds__(512, 4) void k_mega(const unsigned short* __restrict__ t1b,
                                                 const unsigned short* __restrict__ nv2b,
                                                 const unsigned short* __restrict__ yT,
                                                 float* __restrict__ part) {
  const int tid = threadIdx.x;
  const int w = tid >> 6, lane = tid & 63, q = lane >> 4, i16 = lane & 15;
  const int wc = w >> 1, wm = w & 1;
  const int mb = blockIdx.x * 128;
  const int nt0 = blockIdx.y * CHUNK;

  __shared__ unsigned short Ew[2][128][ESTR];  // 36864 B

  // gen B-frag (loop-invariant): B[d][m=i16] = nv2[mb + w*16 + i16][d]
  const bf16x8 bg = *(const bf16x8*)(nv2b + (size_t)(mb + w * 16 + i16) * DD + q * 8);

  const f32x4 z4 = {0.f, 0.f, 0.f, 0.f};
  f32x4 acc[3][4];
#pragma unroll
  for (int c = 0; c < 3; ++c)
#pragma unroll
    for (int ms = 0; ms < 4; ++ms) acc[c][ms] = (f32x4){0.f, 0.f, 0.f, 0.f};

  // ---- prologue: generate stage 0 into buf 0 ----
#pragma unroll
  for (int s = 0; s < 4; ++s) {
    bf16x8 at = *(const bf16x8*)(t1b + (size_t)(nt0 + s * 16 + i16) * DD + q * 8);
    f32x4 d = __builtin_amdgcn_mfma_f32_16x16x32_bf16(at, bg, z4, 0, 0, 0);
    bf16x4 e;
#pragma unroll
    for (int r = 0; r < 4; ++r) e[r] = (short)f2bf(fexp2(fmaxf(d[r], 0.f)));
    *(bf16x4*)&Ew[0][w * 16 + i16][s * 16 + q * 4] = e;
  }
  __syncthreads();

  int p = 0;
  for (int st = 0; st < 16; ++st, p ^= 1) {
    const int nt = nt0 + st * 64;
    const bool more = (st < 15);

    // next stage's t1 A-frags (global, issued first)
    bf16x8 atn[4];
    if (more) {
#pragma unroll
      for (int s = 0; s < 4; ++s)
        atn[s] = *(const bf16x8*)(t1b + (size_t)(nt + 64 + s * 16 + i16) * DD + q * 8);
    }

    // half-0 operands
    bf16x8 yfr[3], efr[4];
#pragma unroll
    for (int c = 0; c < 3; ++c)
      yfr[c] = *(const bf16x8*)(yT + (size_t)((wc * 3 + c) * 16 + i16) * NN + nt + q * 8);
#pragma unroll
    for (int ms = 0; ms < 4; ++ms)
      efr[ms] = *(const bf16x8*)&Ew[p][wm * 64 + ms * 16 + i16][q * 8];

    // gen first half (s0,s1) for stage st+1
    f32x4 d0, d1;
    if (more) {
      d0 = __builtin_amdgcn_mfma_f32_16x16x32_bf16(atn[0], bg, z4, 0, 0, 0);
      d1 = __builtin_amdgcn_mfma_f32_16x16x32_bf16(atn[1], bg, z4, 0, 0, 0);
    }

    // acc half-0 (12 MFMAs)
#pragma unroll
    for (int c = 0; c < 3; ++c)
#pragma unroll
      for (int ms = 0; ms < 4; ++ms)
        acc[c][ms] = __builtin_amdgcn_mfma_f32_16x16x32_bf16(yfr[c], efr[ms], acc[c][ms], 0, 0, 0);

    // exp2 + store s0,s1; gen + store s2,s3 (VALU overlaps MFMA pipes)
    if (more) {
      bf16x4 e0, e1;
#pragma unroll
      for (int r = 0; r < 4; ++r) {
        e0[r] = (short)f2bf(fexp2(fmaxf(d0[r], 0.f)));
        e1[r] = (short)f2bf(fexp2(fmaxf(d1[r], 0.f)));
      }
      *(bf16x4*)&Ew[p ^ 1][w * 16 + i16][q * 4] = e0;
      *(bf16x4*)&Ew[p ^ 1][w * 16 + i16][16 + q * 4] = e1;
      f32x4 d2 = __builtin_amdgcn_mfma_f32_16x16x32_bf16(atn[2], bg, z4, 0, 0, 0);
      f32x4 d3 = __builtin_amdgcn_mfma_f32_16x16x32_bf16(atn[3], bg, z4, 0, 0, 0);
      bf16x4 e2, e3;
#pragma unroll
      for (int r = 0; r < 4; ++r) {
        e2[r] = (short)f2bf(fexp2(fmaxf(d2[r], 0.f)));
        e3[r] = (short)f2bf(fexp2(fmaxf(d3[r], 0.f)));
      }
      *(bf16x4*)&Ew[p ^ 1][w * 16 + i16][32 + q * 4] = e2;
      *(bf16x4*)&Ew[p ^ 1][w * 16 + i16][48 + q * 4] = e3;
    }

    // half-1 operands + acc (12 MFMAs)
#pragma unroll
    for (int c = 0; c < 3; ++c)
      yfr[c] = *(const bf16x8*)(yT + (size_t)((wc * 3 + c) * 16 + i16) * NN + nt + 32 + q * 8);
#pragma unroll
    for (int ms = 0; ms < 4; ++ms)
      efr[ms] = *(const bf16x8*)&Ew[p][wm * 64 + ms * 16 + i16][32 + q * 8];
#pragma unroll
    for (int c = 0; c < 3; ++c)
#pragma unroll
      for (int ms = 0; ms < 4; ++ms)
        acc[c][ms] = __builtin_amdgcn_mfma_f32_16x16x32_bf16(yfr[c], efr[ms], acc[c][ms], 0, 0, 0);

    __syncthreads();  // buf p reads done; buf p^1 writes visible
  }

  // epilogue: lane holds col = (wc*3+c)*16 + q*4 + r, m = mb + wm*64 + ms*16 + i16
  float* pp = part + (size_t)blockIdx.y * 192 * NN;
#pragma unroll
  for (int c = 0; c < 3; ++c)
#pragma unroll
    for (int ms = 0; ms < 4; ++ms) {
      const int colbase = (wc * 3 + c) * 16 + q * 4;
      const int m = mb + wm * 64 + ms * 16 + i16;
#pragma unroll
      for (int r = 0; r < 4; ++r)
        pp[(size_t)(colbase + r) * NN + m] = acc[c][ms][r];
    }
}

// ---- reduce NSPLIT partials + transpose to out[bc][m][t] ----
__global__ __launch_bounds__(256) void k_reduce(const float* __restrict__ part,
                                                float* __restrict__ out) {
  __shared__ float os[3072];
  const int tid = threadIdx.x;
  const int m0 = blockIdx.x * 256;
  const int bc = blockIdx.y;
#pragma unroll
  for (int t = 0; t < 12; ++t) {
    const int col = bc * TT + t;
    float s = 0.f;
#pragma unroll
    for (int nc = 0; nc < NSPLIT; ++nc)
      s += part[((size_t)nc * 192 + col) * NN + m0 + tid];
    os[tid * 12 + t] = s;
  }
  __syncthreads();
  float* op = out + (size_t)bc * NN * TT + (size_t)m0 * TT;
#pragma unroll
  for (int j = 0; j < 12; ++j) op[j * 256 + tid] = os[j * 256 + tid];
}

extern "C" void kernel_launch(void* const* d_in, const int* in_sizes, int n_in,
                              void* d_out, int out_size, void* d_ws, size_t ws_size,
                              hipStream_t stream) {
  const float* x = (const float*)d_in[0];
  const float* nv1 = (const float*)d_in[1];
  const float* nv2 = (const float*)d_in[2];
  const float* tv = (const float*)d_in[3];
  const float* kk = (const float*)d_in[4];
  const int* tind = (const int*)d_in[5];
  float* out = (float*)d_out;

  char* ws = (char*)d_ws;
  unsigned short* t1b  = (unsigned short*)(ws);            //  524288 B
  unsigned short* nv2b = (unsigned short*)(ws + 524288);   //  524288 B
  float* sums          = (float*)(ws + 1048576);           //   32768 B
  unsigned short* yT   = (unsigned short*)(ws + 1081344);  // 3145728 B -> 4227072
  float* part          = (float*)(ws + 4227072);           // 50331648 B -> 54558720 (~55 MB)

  hipMemsetAsync(sums, 0, NN * sizeof(float), stream);
  k_prep<<<64, 256, 0, stream>>>(nv1, nv2, tv, kk, tind, t1b, nv2b);
  k_stats<<<dim3(128, 8), 256, 0, stream>>>(t1b, nv2b, sums);
  k_y<<<dim3(32, 16), 256, 0, stream>>>(x, sums, yT);
  k_mega<<<dim3(64, NSPLIT), 512, 0, stream>>>(t1b, nv2b, yT, part);
  k_reduce<<<dim3(32, 16), 256, 0, stream>>>(part, out);
}